// Round 5
// baseline (592.542 us; speedup 1.0000x reference)
//
#include <hip/hip_runtime.h>
#include <stdint.h>
#include <stddef.h>

// ---------------------------------------------------------------------------
// Qwen2 decoder layer, MI355X (gfx950).
// B=2 S=2048 H=896 NH=7 NKV=1 D=128 I=4864.  M = B*S = 4096 rows.
// Round 5: gate/up -> single fused 256x128(x2) BK=32 counted-vmcnt pipelined
// GEMM with SiLU*up epilogue (no gu intermediate; ws footprint = round 3's,
// which passed). Everything else identical to the round-3 source.
// ---------------------------------------------------------------------------

typedef unsigned short u16;
typedef unsigned long long u64;
typedef __bf16 bf16x8 __attribute__((ext_vector_type(8)));
typedef u16    u16x8  __attribute__((ext_vector_type(8)));
typedef float  f32x4  __attribute__((ext_vector_type(4)));

__device__ inline float b2f(u16 u) {
  union { unsigned int i; float f; } v; v.i = ((unsigned int)u) << 16; return v.f;
}
__device__ inline u16 f2b(float f) {
  union { float f; unsigned int i; } v; v.f = f;
  unsigned int r = v.i + 0x7FFFu + ((v.i >> 16) & 1u);   // RNE
  return (u16)(r >> 16);
}

__device__ inline f32x4 mfma16(bf16x8 a, bf16x8 b, f32x4 c) {
  return __builtin_amdgcn_mfma_f32_16x16x32_bf16(a, b, c, 0, 0, 0);
}

// async global->LDS, 16B per lane. LDS dest is wave-uniform base (+lane*16 by HW).
__device__ inline void gload_lds16(const u16* g, u16* l) {
  __builtin_amdgcn_global_load_lds((__attribute__((address_space(1))) void*)g,
                                   (__attribute__((address_space(3))) void*)l,
                                   16, 0, 0);
}

template<int ITERS>
__device__ inline void stage_lds64(const u16* __restrict__ g, int ld, u16* lds, int t) {
  int wub = t & 192;                       // wave-uniform part of t
  #pragma unroll
  for (int i = 0; i < ITERS; ++i) {
    int e8 = i * 256 + t;
    int r = e8 >> 3, c = (e8 & 7) << 3;    // 8 chunks per 64-elem row
    gload_lds16(g + (size_t)r * ld + c, lds + (i * 256 + wub) * 8);
  }
}

// ---------------------------------------------------------------------------
// Dtype probe (fp32 vs bf16 input buffers).
// ---------------------------------------------------------------------------
__global__ __launch_bounds__(256) void detect_k(const unsigned int* __restrict__ x,
                                                int* __restrict__ flag) {
  __shared__ int red[4];
  int t = threadIdx.x;
  int weird = 0;
  #pragma unroll
  for (int i = 0; i < 4; ++i) {
    unsigned int w = x[t * 4 + i];
    float a = fabsf(b2f((u16)(w & 0xFFFF)));
    if (!(a <= 1e5f)) weird++;
    else if (a != 0.0f && a < 1e-30f) weird++;
  }
  #pragma unroll
  for (int off = 32; off; off >>= 1) weird += __shfl_xor(weird, off);
  if ((t & 63) == 0) red[t >> 6] = weird;
  __syncthreads();
  if (t == 0) flag[0] = (red[0] + red[1] + red[2] + red[3] > 64) ? 1 : 0;
}

// ---------------------------------------------------------------------------
// Batched input normalization: 15 tensors -> bf16 copies in ws.
// ---------------------------------------------------------------------------
struct CvtJob { const void* src; u16* dst; int n; };
struct CvtJobs { CvtJob j[15]; };

__global__ __launch_bounds__(256) void convert_k(CvtJobs jobs, const int* __restrict__ flag) {
  CvtJob c = jobs.j[blockIdx.y];
  int idx = (blockIdx.x * 256 + threadIdx.x) * 8;
  if (idx >= c.n) return;
  if (*flag) {
    const float* s = (const float*)c.src;
    u16x8 o;
    #pragma unroll
    for (int i = 0; i < 8; ++i) o[i] = f2b(s[idx + i]);
    *(u16x8*)(c.dst + idx) = o;
  } else {
    *(u16x8*)(c.dst + idx) = *(const u16x8*)((const u16*)c.src + idx);
  }
}

// ---------------------------------------------------------------------------
// RMSNorm: rows of 896, block = 448 threads (7 waves), 2 elems/thread.
// ---------------------------------------------------------------------------
__global__ __launch_bounds__(448) void rmsnorm_k(const u16* __restrict__ x,
                                                 const u16* __restrict__ w,
                                                 u16* __restrict__ out) {
  __shared__ float red[7];
  int t = threadIdx.x;
  size_t row = blockIdx.x;
  const u16* xr = x + row * 896;
  unsigned int pair = *(const unsigned int*)&xr[t * 2];
  float v0 = b2f((u16)(pair & 0xFFFF)), v1 = b2f((u16)(pair >> 16));
  float ss = v0 * v0 + v1 * v1;
  #pragma unroll
  for (int off = 32; off; off >>= 1) ss += __shfl_xor(ss, off);
  if ((t & 63) == 0) red[t >> 6] = ss;
  __syncthreads();
  float tot = red[0] + red[1] + red[2] + red[3] + red[4] + red[5] + red[6];
  float inv = rsqrtf(tot * (1.0f / 896.0f) + 1e-6f);
  unsigned int wp = *(const unsigned int*)&w[t * 2];
  unsigned int o = (unsigned int)f2b(v0 * inv * b2f((u16)(wp & 0xFFFF)))
                 | ((unsigned int)f2b(v1 * inv * b2f((u16)(wp >> 16))) << 16);
  *(unsigned int*)&out[row * 896 + t * 2] = o;
}

// ---------------------------------------------------------------------------
// QKV GEMM: A(4096x896) @ [wq;wk;wv]^T + bias -> qkv(4096x1152).
// ---------------------------------------------------------------------------
__global__ __launch_bounds__(256) void gemm_qkv(const u16* __restrict__ A,
    const u16* __restrict__ wq, const u16* __restrict__ bq,
    const u16* __restrict__ wk, const u16* __restrict__ bk,
    const u16* __restrict__ wv, const u16* __restrict__ bv,
    u16* __restrict__ C) {
  __shared__ u16 As[128 * 64], Bs[128 * 64];
  int t = threadIdx.x, lane = t & 63, w = t >> 6;
  int wm = w >> 1, wn = w & 1, lrow = lane & 15, lg = lane >> 4;
  int bx = blockIdx.x, row0 = blockIdx.y * 128;
  const u16 *W, *bias; int ocol;
  if (bx < 7)       { W = wq + (size_t)bx * 128 * 896; bias = bq + bx * 128; ocol = bx * 128; }
  else if (bx == 7) { W = wk; bias = bk; ocol = 896; }
  else              { W = wv; bias = bv; ocol = 1024; }

  f32x4 acc[4][4] = {};
  for (int kt = 0; kt < 896; kt += 64) {
    stage_lds64<4>(A + (size_t)row0 * 896 + kt, 896, As, t);
    stage_lds64<4>(W + kt, 896, Bs, t);
    __syncthreads();
    #pragma unroll
    for (int kk = 0; kk < 2; ++kk) {
      bf16x8 af[4], bf[4];
      #pragma unroll
      for (int m = 0; m < 4; ++m)
        af[m] = *(const bf16x8*)&As[(wm * 64 + m * 16 + lrow) * 64 + kk * 32 + lg * 8];
      #pragma unroll
      for (int n = 0; n < 4; ++n)
        bf[n] = *(const bf16x8*)&Bs[(wn * 64 + n * 16 + lrow) * 64 + kk * 32 + lg * 8];
      #pragma unroll
      for (int m = 0; m < 4; ++m)
        #pragma unroll
        for (int n = 0; n < 4; ++n)
          acc[m][n] = mfma16(af[m], bf[n], acc[m][n]);
    }
    __syncthreads();
  }
  #pragma unroll
  for (int m = 0; m < 4; ++m)
    #pragma unroll
    for (int n = 0; n < 4; ++n) {
      int col = wn * 64 + n * 16 + lrow;
      float bb = b2f(bias[col]);
      #pragma unroll
      for (int j = 0; j < 4; ++j) {
        size_t row = row0 + wm * 64 + m * 16 + lg * 4 + j;
        C[row * 1152 + ocol + col] = f2b(acc[m][n][j] + bb);
      }
    }
}

// ---------------------------------------------------------------------------
// Generic C = A @ W^T (+ residual). BM=BN=128, BK=64.
// DYNOUT: branch output dtype on *flag (1=fp32, 0=bf16).
// ---------------------------------------------------------------------------
template<bool RES, bool DYNOUT>
__global__ __launch_bounds__(256) void gemm_bt(const u16* __restrict__ A,
    const u16* __restrict__ W, const u16* __restrict__ resid,
    void* __restrict__ Cp, const int* __restrict__ flag, int K, int ldc) {
  __shared__ u16 As[128 * 64], Bs[128 * 64];
  int t = threadIdx.x, lane = t & 63, w = t >> 6;
  int wm = w >> 1, wn = w & 1, lrow = lane & 15, lg = lane >> 4;
  int col0 = blockIdx.x * 128, row0 = blockIdx.y * 128;
  int f32out = DYNOUT ? *flag : 0;

  f32x4 acc[4][4] = {};
  for (int kt = 0; kt < K; kt += 64) {
    stage_lds64<4>(A + (size_t)row0 * K + kt, K, As, t);
    stage_lds64<4>(W + (size_t)col0 * K + kt, K, Bs, t);
    __syncthreads();
    #pragma unroll
    for (int kk = 0; kk < 2; ++kk) {
      bf16x8 af[4], bf[4];
      #pragma unroll
      for (int m = 0; m < 4; ++m)
        af[m] = *(const bf16x8*)&As[(wm * 64 + m * 16 + lrow) * 64 + kk * 32 + lg * 8];
      #pragma unroll
      for (int n = 0; n < 4; ++n)
        bf[n] = *(const bf16x8*)&Bs[(wn * 64 + n * 16 + lrow) * 64 + kk * 32 + lg * 8];
      #pragma unroll
      for (int m = 0; m < 4; ++m)
        #pragma unroll
        for (int n = 0; n < 4; ++n)
          acc[m][n] = mfma16(af[m], bf[n], acc[m][n]);
    }
    __syncthreads();
  }
  #pragma unroll
  for (int m = 0; m < 4; ++m)
    #pragma unroll
    for (int n = 0; n < 4; ++n) {
      int col = col0 + wn * 64 + n * 16 + lrow;
      #pragma unroll
      for (int j = 0; j < 4; ++j) {
        size_t row = row0 + wm * 64 + m * 16 + lg * 4 + j;
        float v = acc[m][n][j];
        if (RES) v += b2f(resid[row * (size_t)ldc + col]);
        if (DYNOUT && f32out) ((float*)Cp)[row * (size_t)ldc + col] = v;
        else                  ((u16*)Cp)[row * (size_t)ldc + col] = f2b(v);
      }
    }
}

// ---------------------------------------------------------------------------
// Fused gate/up GEMM + SiLU*up, 256-row x 128-col tiles (x2 weights), BK=32.
// 512 thr (8 waves, 2M x 4N). 3-deep LDS pipeline, counted vmcnt(4) (never 0
// mid-loop), lgkmcnt(0) read-drain BEFORE the single s_barrier per tile.
// Pair-interleaved LDS layout: chunk(r,k8) stored at l=((r>>1)<<3)|((r&1)<<2)|k8idx
// -> wave frag reads are 64 consecutive 16B chunks (conflict-free), and the
// staging store is gload_lds-linear with a per-lane source permutation.
// B-tile rows 0..127 = wg[col0..col0+127], rows 128..255 = wu[col0..col0+127].
// ---------------------------------------------------------------------------
__global__ __launch_bounds__(512, 2) void gemm_gateup256(const u16* __restrict__ A,
    const u16* __restrict__ Wg, const u16* __restrict__ Wu,
    u16* __restrict__ act) {
  __shared__ u16 Abuf[3][256 * 32];
  __shared__ u16 Bbuf[3][256 * 32];
  int t = threadIdx.x, lane = t & 63, w = t >> 6;
  int wm = w >> 2, wn = w & 3;            // 2 x 4 wave grid
  int lrow = lane & 15, lg = lane >> 4;
  const int nbx = 38;                     // 4864 / 128 col-tiles
  int bid = blockIdx.x;
  int sw = (bid & 7) * 76 + (bid >> 3);   // 608 = 8 * 76, bijective XCD swizzle
  int bx = sw % nbx, by = sw / nbx;
  int col0 = bx * 128, row0 = by * 256;
  const u16* Ab  = A  + (size_t)row0 * 896;
  const u16* Wgb = Wg + (size_t)col0 * 896;
  const u16* Wub = Wu + (size_t)col0 * 896;
  const int NT = 28;                      // 896 / 32

  int sl = t;                             // staging lane-slot
  int sr = ((sl >> 3) << 1) | ((sl >> 2) & 1);   // row 0..127
  int sk = (sl & 3) << 3;                 // k8 offset
  auto stage = [&](int tt, int buf) {
    const u16* ga = Ab + tt * 32;
    // A rows 0..127 (p=0) and 128..255 (p=1)
    gload_lds16(ga + (size_t)sr * 896 + sk,          &Abuf[buf][(t & 448) * 8]);
    gload_lds16(ga + (size_t)(128 + sr) * 896 + sk,  &Abuf[buf][(512 + (t & 448)) * 8]);
    // B: gate rows (p=0), up rows (p=1)
    gload_lds16(Wgb + (size_t)sr * 896 + tt * 32 + sk, &Bbuf[buf][(t & 448) * 8]);
    gload_lds16(Wub + (size_t)sr * 896 + tt * 32 + sk, &Bbuf[buf][(512 + (t & 448)) * 8]);
  };

  f32x4 accg[8][2] = {}, accu[8][2] = {};
  stage(0, 0);
  stage(1, 1);
  int buf = 0;
  for (int tt = 0; tt < NT; ++tt) {
    if (tt == NT - 1) asm volatile("s_waitcnt vmcnt(0)" ::: "memory");
    else              asm volatile("s_waitcnt vmcnt(4)" ::: "memory");
    asm volatile("s_waitcnt lgkmcnt(0)" ::: "memory");
    __builtin_amdgcn_sched_barrier(0);
    __builtin_amdgcn_s_barrier();
    __builtin_amdgcn_sched_barrier(0);
    if (tt + 2 < NT) {
      int nb = buf + 2; if (nb >= 3) nb -= 3;
      stage(tt + 2, nb);
    }
    const u16* Ac = Abuf[buf];
    const u16* Bc = Bbuf[buf];
    bf16x8 af[8], bg[2], bu[2];
    #pragma unroll
    for (int m = 0; m < 8; ++m) {
      int r = wm * 128 + m * 16 + lrow;
      af[m] = *(const bf16x8*)&Ac[(((r >> 1) << 3) | ((r & 1) << 2) | lg) << 3];
    }
    #pragma unroll
    for (int n = 0; n < 2; ++n) {
      int r = wn * 32 + n * 16 + lrow;
      int l = ((r >> 1) << 3) | ((r & 1) << 2) | lg;
      bg[n] = *(const bf16x8*)&Bc[l << 3];
      bu[n] = *(const bf16x8*)&Bc[(512 + l) << 3];
    }
    __builtin_amdgcn_s_setprio(1);
    #pragma unroll
    for (int m = 0; m < 8; ++m)
      #pragma unroll
      for (int n = 0; n < 2; ++n) {
        accg[m][n] = mfma16(af[m], bg[n], accg[m][n]);
        accu[m][n] = mfma16(af[m], bu[n], accu[m][n]);
      }
    __builtin_amdgcn_s_setprio(0);
    ++buf; if (buf >= 3) buf -= 3;
  }
  #pragma unroll
  for (int m = 0; m < 8; ++m)
    #pragma unroll
    for (int n = 0; n < 2; ++n) {
      int col = col0 + wn * 32 + n * 16 + lrow;
      #pragma unroll
      for (int j = 0; j < 4; ++j) {
        size_t row = row0 + wm * 128 + m * 16 + lg * 4 + j;
        float g = accg[m][n][j], u = accu[m][n][j];
        act[row * 4864 + col] = f2b(g / (1.0f + __expf(-g)) * u);
      }
    }
}

// ---------------------------------------------------------------------------
// RoPE in-place on q (7 heads) and k (1 head) inside qkv(4096 x 1152).
// ---------------------------------------------------------------------------
__global__ __launch_bounds__(256) void rope_k(u16* __restrict__ qkv,
                                              const u16* __restrict__ cosb,
                                              const u16* __restrict__ sinb) {
  int t = threadIdx.x;
  int d = t & 63, hsub = t >> 6;
  int hidx = blockIdx.x * 4 + hsub;     // 0..7 (7 = the single k head)
  size_t row = blockIdx.y;              // 0..4095
  int s = (int)(row & 2047);
  int cb = hidx < 7 ? hidx * 128 : 896;
  u16* p = qkv + row * 1152 + cb;
  float x1 = b2f(p[d]), x2 = b2f(p[d + 64]);
  float c = b2f(cosb[s * 128 + d]), sn = b2f(sinb[s * 128 + d]);
  p[d]      = f2b(x1 * c - x2 * sn);
  p[d + 64] = f2b(x1 * sn + x2 * c);
}

// ---------------------------------------------------------------------------
// Flash attention: paired causal q-tiles, KVBLK=64, swizzled LDS.
// ---------------------------------------------------------------------------
__device__ inline void stageK_sw(u16* dst, const u16* kb, int k0, int t) {
  #pragma unroll
  for (int i = 0; i < 4; ++i) {
    int c = i * 256 + t;
    int row = c >> 4;
    int colb = ((c & 15) << 4) ^ ((row & 7) << 4);   // pre-swizzled source col
    gload_lds16(kb + (size_t)(k0 + row) * 1152 + (colb >> 1),
                dst + (i * 256 + (t & 192)) * 8);
  }
}
__device__ inline void loadV(u16x8* vr, const u16* vb, int k0, int t) {
  int kq = (t & 15) * 4, d0 = (t >> 4) * 8;
  #pragma unroll
  for (int i = 0; i < 4; ++i)
    vr[i] = *(const u16x8*)(vb + (size_t)(k0 + kq + i) * 1152 + d0);
}
__device__ inline void writeVt(u16* VtB, const u16x8* vr, int t) {
  int kq = (t & 15) * 4, d0 = (t >> 4) * 8;
  #pragma unroll
  for (int dj = 0; dj < 8; ++dj) {
    int d = d0 + dj;
    u64 val = (u64)vr[0][dj] | ((u64)vr[1][dj] << 16)
            | ((u64)vr[2][dj] << 32) | ((u64)vr[3][dj] << 48);
    *(u64*)((char*)VtB + ((d * 128 + kq * 2) ^ ((d & 7) << 4))) = val;
  }
}
__device__ inline bf16x8 ldSw(const u16* buf, int row, int stride, int colbyte) {
  int byte = (row * stride + colbyte) ^ ((row & 7) << 4);
  return *(const bf16x8*)((const char*)buf + byte);
}

__device__ inline void smax_tile(f32x4* sa, int q0, int k0, bool diag,
                                 float* m_run, float* l_run, f32x4* oa,
                                 u16* PsW, int lrow, int lg) {
  const float SC = 0.12753102f;   // D^-0.5 * log2(e)
  float s[4][4], mx[4];
  #pragma unroll
  for (int j = 0; j < 4; ++j) {
    int qrow = q0 + lg * 4 + j;
    #pragma unroll
    for (int nf = 0; nf < 4; ++nf) {
      float v = sa[nf][j] * SC;
      if (diag && (k0 + nf * 16 + lrow > qrow)) v = -1e30f;
      s[nf][j] = v;
    }
    mx[j] = fmaxf(fmaxf(s[0][j], s[1][j]), fmaxf(s[2][j], s[3][j]));
  }
  #pragma unroll
  for (int off = 1; off < 16; off <<= 1)
    #pragma unroll
    for (int j = 0; j < 4; ++j) mx[j] = fmaxf(mx[j], __shfl_xor(mx[j], off));
  float ps[4];
  #pragma unroll
  for (int j = 0; j < 4; ++j) {
    float mn = fmaxf(m_run[j], mx[j]);
    float al = exp2f(m_run[j] - mn);
    m_run[j] = mn;
    float sum = 0.0f;
    #pragma unroll
    for (int nf = 0; nf < 4; ++nf) {
      float pv = exp2f(s[nf][j] - mn);
      s[nf][j] = pv; sum += pv;
    }
    ps[j] = sum;
    l_run[j] *= al;
    #pragma unroll
    for (int nf2 = 0; nf2 < 8; ++nf2) oa[nf2][j] *= al;
  }
  #pragma unroll
  for (int off = 1; off < 16; off <<= 1)
    #pragma unroll
    for (int j = 0; j < 4; ++j) ps[j] += __shfl_xor(ps[j], off);
  #pragma unroll
  for (int j = 0; j < 4; ++j) l_run[j] += ps[j];
  #pragma unroll
  for (int j = 0; j < 4; ++j) {
    int row = lg * 4 + j;
    #pragma unroll
    for (int nf = 0; nf < 4; ++nf) {
      int byte = (row * 128 + (nf * 16 + lrow) * 2) ^ ((row & 7) << 4);
      *(u16*)((char*)PsW + byte) = f2b(s[nf][j]);
    }
  }
}

__global__ __launch_bounds__(256) void attn_k(const u16* __restrict__ qkv,
                                              u16* __restrict__ out) {
  __shared__ u16 Ks[2][64 * 128];
  __shared__ u16 Vt[2][128 * 64];
  __shared__ u16 Ps[4][2][16 * 64];
  int t = threadIdx.x, lane = t & 63, w = t >> 6;
  int lrow = lane & 15, lg = lane >> 4;
  int p = blockIdx.x, bh = blockIdx.y;
  int b = bh / 7, h = bh % 7;
  int tA = p, tB = 31 - p;
  int qA = tA * 64 + w * 16, qB = tB * 64 + w * 16;
  const u16* base = qkv + (size_t)b * 2048 * 1152;
  const u16* kb = base + 896;
  const u16* vb = base + 1024;

  bf16x8 qfA[4], qfB[4];
  #pragma unroll
  for (int kk = 0; kk < 4; ++kk) {
    qfA[kk] = *(const bf16x8*)(base + (size_t)(qA + lrow) * 1152 + h * 128 + kk * 32 + lg * 8);
    qfB[kk] = *(const bf16x8*)(base + (size_t)(qB + lrow) * 1152 + h * 128 + kk * 32 + lg * 8);
  }
  f32x4 oaA[8] = {}, oaB[8] = {};
  float mA[4], lA[4], mB[4], lB[4];
  #pragma unroll
  for (int j = 0; j < 4; ++j) { mA[j] = -1e30f; lA[j] = 0.0f; mB[j] = -1e30f; lB[j] = 0.0f; }

  stageK_sw(Ks[0], kb, 0, t);
  { u16x8 vr[4]; loadV(vr, vb, 0, t); writeVt(Vt[0], vr, t); }
  __syncthreads();

  int cur = 0;
  int ktmax = tB;
  for (int kt = 0; kt <= ktmax; ++kt) {
    bool pre = kt < ktmax;
    u16x8 vr2[4];
    if (pre) { stageK_sw(Ks[cur ^ 1], kb, (kt + 1) * 64, t); loadV(vr2, vb, (kt + 1) * 64, t); }

    bool doA = (kt <= tA);
    int k0 = kt * 64;
    const u16* KsC = Ks[cur];
    const u16* VtC = Vt[cur];

    f32x4 saA[4] = {}, saB[4] = {};
    #pragma unroll
    for (int nf = 0; nf < 4; ++nf) {
      bf16x8 kf[4];
      #pragma unroll
      for (int kk = 0; kk < 4; ++kk)
        kf[kk] = ldSw(KsC, nf * 16 + lrow, 256, kk * 64 + lg * 16);
      #pragma unroll
      for (int kk = 0; kk < 4; ++kk)
        saB[nf] = mfma16(qfB[kk], kf[kk], saB[nf]);
      if (doA)
        #pragma unroll
        for (int kk = 0; kk < 4; ++kk)
          saA[nf] = mfma16(qfA[kk], kf[kk], saA[nf]);
    }

    if (doA) smax_tile(saA, qA, k0, kt == tA, mA, lA, oaA, Ps[w][0], lrow, lg);
    smax_tile(saB, qB, k0, kt == tB, mB, lB, oaB, Ps[w][1], lrow, lg);

    bf16x8 pfA[2], pfB[2];
    #pragma unroll
    for (int ks = 0; ks < 2; ++ks) {
      pfB[ks] = ldSw(Ps[w][1], lrow, 128, ks * 64 + lg * 16);
      if (doA) pfA[ks] = ldSw(Ps[w][0], lrow, 128, ks * 64 + lg * 16);
    }
    #pragma unroll
    for (int ks = 0; ks < 2; ++ks) {
      bf16x8 vf[8];
      #pragma unroll
      for (int nf2 = 0; nf2 < 8; ++nf2)
        vf[nf2] = ldSw(VtC, nf2 * 16 + lrow, 128, ks * 64 + lg * 16);
      #pragma unroll
      for (int nf2 = 0; nf2 < 8; ++nf2)
        oaB[nf2] = mfma16(pfB[ks], vf[nf2], oaB[nf2]);
      if (doA)
        #pragma unroll
        for (int nf2 = 0; nf2 < 8; ++nf2)
          oaA[nf2] = mfma16(pfA[ks], vf[nf2], oaA[nf2]);
    }

    if (pre) writeVt(Vt[cur ^ 1], vr2, t);
    __syncthreads();
    cur ^= 1;
  }

  #pragma unroll
  for (int tile = 0; tile < 2; ++tile) {
    int q0 = tile ? qB : qA;
    const f32x4* oa = tile ? oaB : oaA;
    const float* l = tile ? lB : lA;
    u16* ob = out + ((size_t)b * 2048 + q0) * 896 + h * 128;
    #pragma unroll
    for (int j = 0; j < 4; ++j) {
      float rl = 1.0f / l[j];
      #pragma unroll
      for (int nf2 = 0; nf2 < 8; ++nf2)
        ob[(size_t)(lg * 4 + j) * 896 + nf2 * 16 + lrow] = f2b(oa[nf2][j] * rl);
    }
  }
}

// ---------------------------------------------------------------------------
extern "C" void kernel_launch(void* const* d_in, const int* in_sizes, int n_in,
                              void* d_out, int out_size, void* d_ws, size_t ws_size,
                              hipStream_t stream) {
  const int nX = 4096 * 896, nWQ = 896 * 896, nBQ = 896, nWK = 128 * 896, nBK = 128;
  const int nWV = 128 * 896, nBV = 128, nWO = 896 * 896;
  const int nWG = 4864 * 896, nWU = 4864 * 896, nWD = 896 * 4864;
  const int nLN = 896, nCS = 2048 * 128;

  u16* ws = (u16*)d_ws;
  int* flag = (int*)ws;
  size_t off = 16;
  auto alloc = [&](size_t n) { u16* p = ws + off; off += n; return p; };
  u16* cx   = alloc(nX);
  u16* cwq  = alloc(nWQ);  u16* cbq = alloc(nBQ);
  u16* cwk  = alloc(nWK);  u16* cbk = alloc(nBK);
  u16* cwv  = alloc(nWV);  u16* cbv = alloc(nBV);
  u16* cwo  = alloc(nWO);
  u16* cwg  = alloc(nWG);  u16* cwu = alloc(nWU);  u16* cwd = alloc(nWD);
  u16* cln1 = alloc(nLN);  u16* cln2 = alloc(nLN);
  u16* ccos = alloc(nCS);  u16* csin = alloc(nCS);
  u16* h    = alloc(4096 * 896);
  u16* qkv  = alloc(4096 * 1152);
  u16* attn = alloc(4096 * 896);
  u16* x2   = alloc(4096 * 896);
  u16* act  = alloc((size_t)4096 * 4864);

  detect_k<<<1, 256, 0, stream>>>((const unsigned int*)d_in[0], flag);

  CvtJobs jobs;
  const void* srcs[15] = { d_in[0], d_in[1], d_in[2], d_in[3], d_in[4], d_in[5],
                           d_in[6], d_in[7], d_in[8], d_in[9], d_in[10],
                           d_in[11], d_in[12], d_in[14], d_in[15] };
  u16* dsts[15] = { cx, cwq, cbq, cwk, cbk, cwv, cbv, cwo, cwg, cwu, cwd,
                    cln1, cln2, ccos, csin };
  int  ns[15]   = { nX, nWQ, nBQ, nWK, nBK, nWV, nBV, nWO, nWG, nWU, nWD,
                    nLN, nLN, nCS, nCS };
  for (int i = 0; i < 15; ++i) { jobs.j[i].src = srcs[i]; jobs.j[i].dst = dsts[i]; jobs.j[i].n = ns[i]; }
  convert_k<<<dim3(2128, 15), 256, 0, stream>>>(jobs, flag);

  rmsnorm_k <<<4096, 448, 0, stream>>>(cx, cln1, h);
  gemm_qkv  <<<dim3(9, 32),  256, 0, stream>>>(h, cwq, cbq, cwk, cbk, cwv, cbv, qkv);
  rope_k    <<<dim3(2, 4096), 256, 0, stream>>>(qkv, ccos, csin);
  attn_k    <<<dim3(16, 14), 256, 0, stream>>>(qkv, attn);
  gemm_bt<true, false> <<<dim3(7, 32), 256, 0, stream>>>(attn, cwo, cx, (void*)x2, flag, 896, 896);
  rmsnorm_k <<<4096, 448, 0, stream>>>(x2, cln2, h);
  gemm_gateup256 <<<608, 512, 0, stream>>>(h, cwg, cwu, act);
  gemm_bt<true, true> <<<dim3(7, 32), 256, 0, stream>>>(act, cwd, x2, d_out, flag, 4864, 896);
}

// Round 8
// 546.108 us; speedup vs baseline: 1.0850x; 1.0850x over previous
//
#include <hip/hip_runtime.h>
#include <stdint.h>
#include <stddef.h>

// ---------------------------------------------------------------------------
// Qwen2 decoder layer, MI355X (gfx950).
// B=2 S=2048 H=896 NH=7 NKV=1 D=128 I=4864.  M = B*S = 4096 rows.
// Round 8 (= round 6/7 resubmitted; both prior failures were broker-side:
// r6 bare "failed twice" with no timing block, r7 explicit
// GPUAcquisitionTimeout — this source has never run on HW):
//  (1) gateup256 4-deep LDS pipeline (prefetch 3 iters ahead, 128KB LDS);
//  (2) down-proj split-K=2 single dispatch (448 blocks) with fp32+bf16
//      partials in dead ws regions + fused reduce(+residual, dyn out).
// Everything else identical to round-5 (passed, 592.5us).
// ---------------------------------------------------------------------------

typedef unsigned short u16;
typedef unsigned long long u64;
typedef __bf16 bf16x8 __attribute__((ext_vector_type(8)));
typedef u16    u16x8  __attribute__((ext_vector_type(8)));
typedef u16    u16x4  __attribute__((ext_vector_type(4)));
typedef float  f32x4  __attribute__((ext_vector_type(4)));

__device__ inline float b2f(u16 u) {
  union { unsigned int i; float f; } v; v.i = ((unsigned int)u) << 16; return v.f;
}
__device__ inline u16 f2b(float f) {
  union { float f; unsigned int i; } v; v.f = f;
  unsigned int r = v.i + 0x7FFFu + ((v.i >> 16) & 1u);   // RNE
  return (u16)(r >> 16);
}

__device__ inline f32x4 mfma16(bf16x8 a, bf16x8 b, f32x4 c) {
  return __builtin_amdgcn_mfma_f32_16x16x32_bf16(a, b, c, 0, 0, 0);
}

// async global->LDS, 16B per lane. LDS dest is wave-uniform base (+lane*16 by HW).
__device__ inline void gload_lds16(const u16* g, u16* l) {
  __builtin_amdgcn_global_load_lds((__attribute__((address_space(1))) void*)g,
                                   (__attribute__((address_space(3))) void*)l,
                                   16, 0, 0);
}

template<int ITERS>
__device__ inline void stage_lds64(const u16* __restrict__ g, int ld, u16* lds, int t) {
  int wub = t & 192;                       // wave-uniform part of t
  #pragma unroll
  for (int i = 0; i < ITERS; ++i) {
    int e8 = i * 256 + t;
    int r = e8 >> 3, c = (e8 & 7) << 3;    // 8 chunks per 64-elem row
    gload_lds16(g + (size_t)r * ld + c, lds + (i * 256 + wub) * 8);
  }
}

// ---------------------------------------------------------------------------
// Dtype probe (fp32 vs bf16 input buffers).
// ---------------------------------------------------------------------------
__global__ __launch_bounds__(256) void detect_k(const unsigned int* __restrict__ x,
                                                int* __restrict__ flag) {
  __shared__ int red[4];
  int t = threadIdx.x;
  int weird = 0;
  #pragma unroll
  for (int i = 0; i < 4; ++i) {
    unsigned int w = x[t * 4 + i];
    float a = fabsf(b2f((u16)(w & 0xFFFF)));
    if (!(a <= 1e5f)) weird++;
    else if (a != 0.0f && a < 1e-30f) weird++;
  }
  #pragma unroll
  for (int off = 32; off; off >>= 1) weird += __shfl_xor(weird, off);
  if ((t & 63) == 0) red[t >> 6] = weird;
  __syncthreads();
  if (t == 0) flag[0] = (red[0] + red[1] + red[2] + red[3] > 64) ? 1 : 0;
}

// ---------------------------------------------------------------------------
// Batched input normalization: 15 tensors -> bf16 copies in ws.
// ---------------------------------------------------------------------------
struct CvtJob { const void* src; u16* dst; int n; };
struct CvtJobs { CvtJob j[15]; };

__global__ __launch_bounds__(256) void convert_k(CvtJobs jobs, const int* __restrict__ flag) {
  CvtJob c = jobs.j[blockIdx.y];
  int idx = (blockIdx.x * 256 + threadIdx.x) * 8;
  if (idx >= c.n) return;
  if (*flag) {
    const float* s = (const float*)c.src;
    u16x8 o;
    #pragma unroll
    for (int i = 0; i < 8; ++i) o[i] = f2b(s[idx + i]);
    *(u16x8*)(c.dst + idx) = o;
  } else {
    *(u16x8*)(c.dst + idx) = *(const u16x8*)((const u16*)c.src + idx);
  }
}

// ---------------------------------------------------------------------------
// RMSNorm: rows of 896, block = 448 threads (7 waves), 2 elems/thread.
// ---------------------------------------------------------------------------
__global__ __launch_bounds__(448) void rmsnorm_k(const u16* __restrict__ x,
                                                 const u16* __restrict__ w,
                                                 u16* __restrict__ out) {
  __shared__ float red[7];
  int t = threadIdx.x;
  size_t row = blockIdx.x;
  const u16* xr = x + row * 896;
  unsigned int pair = *(const unsigned int*)&xr[t * 2];
  float v0 = b2f((u16)(pair & 0xFFFF)), v1 = b2f((u16)(pair >> 16));
  float ss = v0 * v0 + v1 * v1;
  #pragma unroll
  for (int off = 32; off; off >>= 1) ss += __shfl_xor(ss, off);
  if ((t & 63) == 0) red[t >> 6] = ss;
  __syncthreads();
  float tot = red[0] + red[1] + red[2] + red[3] + red[4] + red[5] + red[6];
  float inv = rsqrtf(tot * (1.0f / 896.0f) + 1e-6f);
  unsigned int wp = *(const unsigned int*)&w[t * 2];
  unsigned int o = (unsigned int)f2b(v0 * inv * b2f((u16)(wp & 0xFFFF)))
                 | ((unsigned int)f2b(v1 * inv * b2f((u16)(wp >> 16))) << 16);
  *(unsigned int*)&out[row * 896 + t * 2] = o;
}

// ---------------------------------------------------------------------------
// QKV GEMM: A(4096x896) @ [wq;wk;wv]^T + bias -> qkv(4096x1152).
// ---------------------------------------------------------------------------
__global__ __launch_bounds__(256) void gemm_qkv(const u16* __restrict__ A,
    const u16* __restrict__ wq, const u16* __restrict__ bq,
    const u16* __restrict__ wk, const u16* __restrict__ bk,
    const u16* __restrict__ wv, const u16* __restrict__ bv,
    u16* __restrict__ C) {
  __shared__ u16 As[128 * 64], Bs[128 * 64];
  int t = threadIdx.x, lane = t & 63, w = t >> 6;
  int wm = w >> 1, wn = w & 1, lrow = lane & 15, lg = lane >> 4;
  int bx = blockIdx.x, row0 = blockIdx.y * 128;
  const u16 *W, *bias; int ocol;
  if (bx < 7)       { W = wq + (size_t)bx * 128 * 896; bias = bq + bx * 128; ocol = bx * 128; }
  else if (bx == 7) { W = wk; bias = bk; ocol = 896; }
  else              { W = wv; bias = bv; ocol = 1024; }

  f32x4 acc[4][4] = {};
  for (int kt = 0; kt < 896; kt += 64) {
    stage_lds64<4>(A + (size_t)row0 * 896 + kt, 896, As, t);
    stage_lds64<4>(W + kt, 896, Bs, t);
    __syncthreads();
    #pragma unroll
    for (int kk = 0; kk < 2; ++kk) {
      bf16x8 af[4], bf[4];
      #pragma unroll
      for (int m = 0; m < 4; ++m)
        af[m] = *(const bf16x8*)&As[(wm * 64 + m * 16 + lrow) * 64 + kk * 32 + lg * 8];
      #pragma unroll
      for (int n = 0; n < 4; ++n)
        bf[n] = *(const bf16x8*)&Bs[(wn * 64 + n * 16 + lrow) * 64 + kk * 32 + lg * 8];
      #pragma unroll
      for (int m = 0; m < 4; ++m)
        #pragma unroll
        for (int n = 0; n < 4; ++n)
          acc[m][n] = mfma16(af[m], bf[n], acc[m][n]);
    }
    __syncthreads();
  }
  #pragma unroll
  for (int m = 0; m < 4; ++m)
    #pragma unroll
    for (int n = 0; n < 4; ++n) {
      int col = wn * 64 + n * 16 + lrow;
      float bb = b2f(bias[col]);
      #pragma unroll
      for (int j = 0; j < 4; ++j) {
        size_t row = row0 + wm * 64 + m * 16 + lg * 4 + j;
        C[row * 1152 + ocol + col] = f2b(acc[m][n][j] + bb);
      }
    }
}

// ---------------------------------------------------------------------------
// Generic C = A @ W^T (+ residual). BM=BN=128, BK=64.
// DYNOUT: branch output dtype on *flag (1=fp32, 0=bf16).
// ---------------------------------------------------------------------------
template<bool RES, bool DYNOUT>
__global__ __launch_bounds__(256) void gemm_bt(const u16* __restrict__ A,
    const u16* __restrict__ W, const u16* __restrict__ resid,
    void* __restrict__ Cp, const int* __restrict__ flag, int K, int ldc) {
  __shared__ u16 As[128 * 64], Bs[128 * 64];
  int t = threadIdx.x, lane = t & 63, w = t >> 6;
  int wm = w >> 1, wn = w & 1, lrow = lane & 15, lg = lane >> 4;
  int col0 = blockIdx.x * 128, row0 = blockIdx.y * 128;
  int f32out = DYNOUT ? *flag : 0;

  f32x4 acc[4][4] = {};
  for (int kt = 0; kt < K; kt += 64) {
    stage_lds64<4>(A + (size_t)row0 * K + kt, K, As, t);
    stage_lds64<4>(W + (size_t)col0 * K + kt, K, Bs, t);
    __syncthreads();
    #pragma unroll
    for (int kk = 0; kk < 2; ++kk) {
      bf16x8 af[4], bf[4];
      #pragma unroll
      for (int m = 0; m < 4; ++m)
        af[m] = *(const bf16x8*)&As[(wm * 64 + m * 16 + lrow) * 64 + kk * 32 + lg * 8];
      #pragma unroll
      for (int n = 0; n < 4; ++n)
        bf[n] = *(const bf16x8*)&Bs[(wn * 64 + n * 16 + lrow) * 64 + kk * 32 + lg * 8];
      #pragma unroll
      for (int m = 0; m < 4; ++m)
        #pragma unroll
        for (int n = 0; n < 4; ++n)
          acc[m][n] = mfma16(af[m], bf[n], acc[m][n]);
    }
    __syncthreads();
  }
  #pragma unroll
  for (int m = 0; m < 4; ++m)
    #pragma unroll
    for (int n = 0; n < 4; ++n) {
      int col = col0 + wn * 64 + n * 16 + lrow;
      #pragma unroll
      for (int j = 0; j < 4; ++j) {
        size_t row = row0 + wm * 64 + m * 16 + lg * 4 + j;
        float v = acc[m][n][j];
        if (RES) v += b2f(resid[row * (size_t)ldc + col]);
        if (DYNOUT && f32out) ((float*)Cp)[row * (size_t)ldc + col] = v;
        else                  ((u16*)Cp)[row * (size_t)ldc + col] = f2b(v);
      }
    }
}

// ---------------------------------------------------------------------------
// Down-proj split-K=2: C = act(4096x4864) @ wd^T(896x4864) + x2, via two
// K-chunks of 2432 in ONE dispatch (grid.z=2 -> 448 blocks, all CUs busy).
// chunk0 -> fp32 partial (+residual) P0; chunk1 -> bf16 partial P1.
// ---------------------------------------------------------------------------
__global__ __launch_bounds__(256) void gemm_down_splitk(const u16* __restrict__ A,
    const u16* __restrict__ W, const u16* __restrict__ resid,
    float* __restrict__ P0, u16* __restrict__ P1) {
  __shared__ u16 As[128 * 64], Bs[128 * 64];
  int t = threadIdx.x, lane = t & 63, w = t >> 6;
  int wm = w >> 1, wn = w & 1, lrow = lane & 15, lg = lane >> 4;
  int col0 = blockIdx.x * 128, row0 = blockIdx.y * 128;
  int k0 = blockIdx.z * 2432;

  f32x4 acc[4][4] = {};
  for (int kt = 0; kt < 2432; kt += 64) {
    stage_lds64<4>(A + (size_t)row0 * 4864 + k0 + kt, 4864, As, t);
    stage_lds64<4>(W + (size_t)col0 * 4864 + k0 + kt, 4864, Bs, t);
    __syncthreads();
    #pragma unroll
    for (int kk = 0; kk < 2; ++kk) {
      bf16x8 af[4], bf[4];
      #pragma unroll
      for (int m = 0; m < 4; ++m)
        af[m] = *(const bf16x8*)&As[(wm * 64 + m * 16 + lrow) * 64 + kk * 32 + lg * 8];
      #pragma unroll
      for (int n = 0; n < 4; ++n)
        bf[n] = *(const bf16x8*)&Bs[(wn * 64 + n * 16 + lrow) * 64 + kk * 32 + lg * 8];
      #pragma unroll
      for (int m = 0; m < 4; ++m)
        #pragma unroll
        for (int n = 0; n < 4; ++n)
          acc[m][n] = mfma16(af[m], bf[n], acc[m][n]);
    }
    __syncthreads();
  }
  #pragma unroll
  for (int m = 0; m < 4; ++m)
    #pragma unroll
    for (int n = 0; n < 4; ++n) {
      int col = col0 + wn * 64 + n * 16 + lrow;
      #pragma unroll
      for (int j = 0; j < 4; ++j) {
        size_t row = row0 + wm * 64 + m * 16 + lg * 4 + j;
        float v = acc[m][n][j];
        if (blockIdx.z == 0) P0[row * 896 + col] = v + b2f(resid[row * 896 + col]);
        else                 P1[row * 896 + col] = f2b(v);
      }
    }
}

// out = P0 + P1 (dyn dtype). 4 elems/thread, 3584 blocks.
__global__ __launch_bounds__(256) void reduce_out_k(const float* __restrict__ p0,
    const u16* __restrict__ p1, void* __restrict__ outp, const int* __restrict__ flag) {
  int i = (blockIdx.x * 256 + threadIdx.x) * 4;
  float4 a = *(const float4*)(p0 + i);
  u16x4 b = *(const u16x4*)(p1 + i);
  float o0 = a.x + b2f(b[0]), o1 = a.y + b2f(b[1]);
  float o2 = a.z + b2f(b[2]), o3 = a.w + b2f(b[3]);
  if (*flag) {
    float4 o = make_float4(o0, o1, o2, o3);
    *(float4*)((float*)outp + i) = o;
  } else {
    u16x4 o = { f2b(o0), f2b(o1), f2b(o2), f2b(o3) };
    *(u16x4*)((u16*)outp + i) = o;
  }
}

// ---------------------------------------------------------------------------
// Fused gate/up GEMM + SiLU*up, 256-row x 128-col tiles (x2 weights), BK=32.
// 512 thr (8 waves, 2M x 4N). 4-deep LDS pipeline (128KB): stage tt issued
// 3 iters ahead (~500cy cover); counted vmcnt(8)/(4)/(0) drains only at end.
// Pair-interleaved LDS layout -> conflict-free frag reads + gload_lds-linear.
// ---------------------------------------------------------------------------
__global__ __launch_bounds__(512, 2) void gemm_gateup256(const u16* __restrict__ A,
    const u16* __restrict__ Wg, const u16* __restrict__ Wu,
    u16* __restrict__ act) {
  __shared__ u16 Abuf[4][256 * 32];
  __shared__ u16 Bbuf[4][256 * 32];
  int t = threadIdx.x, lane = t & 63, w = t >> 6;
  int wm = w >> 2, wn = w & 3;            // 2 x 4 wave grid
  int lrow = lane & 15, lg = lane >> 4;
  const int nbx = 38;                     // 4864 / 128 col-tiles
  int bid = blockIdx.x;
  int sw = (bid & 7) * 76 + (bid >> 3);   // 608 = 8 * 76, bijective XCD swizzle
  int bx = sw % nbx, by = sw / nbx;
  int col0 = bx * 128, row0 = by * 256;
  const u16* Ab  = A  + (size_t)row0 * 896;
  const u16* Wgb = Wg + (size_t)col0 * 896;
  const u16* Wub = Wu + (size_t)col0 * 896;
  const int NT = 28;                      // 896 / 32

  int sl = t;                             // staging lane-slot
  int sr = ((sl >> 3) << 1) | ((sl >> 2) & 1);   // row 0..127
  int sk = (sl & 3) << 3;                 // k8 offset
  auto stage = [&](int tt, int buf) {
    const u16* ga = Ab + tt * 32;
    gload_lds16(ga + (size_t)sr * 896 + sk,          &Abuf[buf][(t & 448) * 8]);
    gload_lds16(ga + (size_t)(128 + sr) * 896 + sk,  &Abuf[buf][(512 + (t & 448)) * 8]);
    gload_lds16(Wgb + (size_t)sr * 896 + tt * 32 + sk, &Bbuf[buf][(t & 448) * 8]);
    gload_lds16(Wub + (size_t)sr * 896 + tt * 32 + sk, &Bbuf[buf][(512 + (t & 448)) * 8]);
  };

  f32x4 accg[8][2] = {}, accu[8][2] = {};
  stage(0, 0);
  stage(1, 1);
  stage(2, 2);
  for (int tt = 0; tt < NT; ++tt) {
    int rem = NT - 1 - tt;                // stages still outstanding beyond tt
    if (rem >= 2)      asm volatile("s_waitcnt vmcnt(8)" ::: "memory");
    else if (rem == 1) asm volatile("s_waitcnt vmcnt(4)" ::: "memory");
    else               asm volatile("s_waitcnt vmcnt(0)" ::: "memory");
    asm volatile("s_waitcnt lgkmcnt(0)" ::: "memory");
    __builtin_amdgcn_sched_barrier(0);
    __builtin_amdgcn_s_barrier();
    __builtin_amdgcn_sched_barrier(0);
    if (tt + 3 < NT) stage(tt + 3, (tt + 3) & 3);
    const u16* Ac = Abuf[tt & 3];
    const u16* Bc = Bbuf[tt & 3];
    bf16x8 af[8], bg[2], bu[2];
    #pragma unroll
    for (int m = 0; m < 8; ++m) {
      int r = wm * 128 + m * 16 + lrow;
      af[m] = *(const bf16x8*)&Ac[(((r >> 1) << 3) | ((r & 1) << 2) | lg) << 3];
    }
    #pragma unroll
    for (int n = 0; n < 2; ++n) {
      int r = wn * 32 + n * 16 + lrow;
      int l = ((r >> 1) << 3) | ((r & 1) << 2) | lg;
      bg[n] = *(const bf16x8*)&Bc[l << 3];
      bu[n] = *(const bf16x8*)&Bc[(512 + l) << 3];
    }
    __builtin_amdgcn_s_setprio(1);
    #pragma unroll
    for (int m = 0; m < 8; ++m)
      #pragma unroll
      for (int n = 0; n < 2; ++n) {
        accg[m][n] = mfma16(af[m], bg[n], accg[m][n]);
        accu[m][n] = mfma16(af[m], bu[n], accu[m][n]);
      }
    __builtin_amdgcn_s_setprio(0);
  }
  #pragma unroll
  for (int m = 0; m < 8; ++m)
    #pragma unroll
    for (int n = 0; n < 2; ++n) {
      int col = col0 + wn * 32 + n * 16 + lrow;
      #pragma unroll
      for (int j = 0; j < 4; ++j) {
        size_t row = row0 + wm * 128 + m * 16 + lg * 4 + j;
        float g = accg[m][n][j], u = accu[m][n][j];
        act[row * 4864 + col] = f2b(g / (1.0f + __expf(-g)) * u);
      }
    }
}

// ---------------------------------------------------------------------------
// RoPE in-place on q (7 heads) and k (1 head) inside qkv(4096 x 1152).
// ---------------------------------------------------------------------------
__global__ __launch_bounds__(256) void rope_k(u16* __restrict__ qkv,
                                              const u16* __restrict__ cosb,
                                              const u16* __restrict__ sinb) {
  int t = threadIdx.x;
  int d = t & 63, hsub = t >> 6;
  int hidx = blockIdx.x * 4 + hsub;     // 0..7 (7 = the single k head)
  size_t row = blockIdx.y;              // 0..4095
  int s = (int)(row & 2047);
  int cb = hidx < 7 ? hidx * 128 : 896;
  u16* p = qkv + row * 1152 + cb;
  float x1 = b2f(p[d]), x2 = b2f(p[d + 64]);
  float c = b2f(cosb[s * 128 + d]), sn = b2f(sinb[s * 128 + d]);
  p[d]      = f2b(x1 * c - x2 * sn);
  p[d + 64] = f2b(x1 * sn + x2 * c);
}

// ---------------------------------------------------------------------------
// Flash attention: paired causal q-tiles, KVBLK=64, swizzled LDS.
// ---------------------------------------------------------------------------
__device__ inline void stageK_sw(u16* dst, const u16* kb, int k0, int t) {
  #pragma unroll
  for (int i = 0; i < 4; ++i) {
    int c = i * 256 + t;
    int row = c >> 4;
    int colb = ((c & 15) << 4) ^ ((row & 7) << 4);   // pre-swizzled source col
    gload_lds16(kb + (size_t)(k0 + row) * 1152 + (colb >> 1),
                dst + (i * 256 + (t & 192)) * 8);
  }
}
__device__ inline void loadV(u16x8* vr, const u16* vb, int k0, int t) {
  int kq = (t & 15) * 4, d0 = (t >> 4) * 8;
  #pragma unroll
  for (int i = 0; i < 4; ++i)
    vr[i] = *(const u16x8*)(vb + (size_t)(k0 + kq + i) * 1152 + d0);
}
__device__ inline void writeVt(u16* VtB, const u16x8* vr, int t) {
  int kq = (t & 15) * 4, d0 = (t >> 4) * 8;
  #pragma unroll
  for (int dj = 0; dj < 8; ++dj) {
    int d = d0 + dj;
    u64 val = (u64)vr[0][dj] | ((u64)vr[1][dj] << 16)
            | ((u64)vr[2][dj] << 32) | ((u64)vr[3][dj] << 48);
    *(u64*)((char*)VtB + ((d * 128 + kq * 2) ^ ((d & 7) << 4))) = val;
  }
}
__device__ inline bf16x8 ldSw(const u16* buf, int row, int stride, int colbyte) {
  int byte = (row * stride + colbyte) ^ ((row & 7) << 4);
  return *(const bf16x8*)((const char*)buf + byte);
}

__device__ inline void smax_tile(f32x4* sa, int q0, int k0, bool diag,
                                 float* m_run, float* l_run, f32x4* oa,
                                 u16* PsW, int lrow, int lg) {
  const float SC = 0.12753102f;   // D^-0.5 * log2(e)
  float s[4][4], mx[4];
  #pragma unroll
  for (int j = 0; j < 4; ++j) {
    int qrow = q0 + lg * 4 + j;
    #pragma unroll
    for (int nf = 0; nf < 4; ++nf) {
      float v = sa[nf][j] * SC;
      if (diag && (k0 + nf * 16 + lrow > qrow)) v = -1e30f;
      s[nf][j] = v;
    }
    mx[j] = fmaxf(fmaxf(s[0][j], s[1][j]), fmaxf(s[2][j], s[3][j]));
  }
  #pragma unroll
  for (int off = 1; off < 16; off <<= 1)
    #pragma unroll
    for (int j = 0; j < 4; ++j) mx[j] = fmaxf(mx[j], __shfl_xor(mx[j], off));
  float ps[4];
  #pragma unroll
  for (int j = 0; j < 4; ++j) {
    float mn = fmaxf(m_run[j], mx[j]);
    float al = exp2f(m_run[j] - mn);
    m_run[j] = mn;
    float sum = 0.0f;
    #pragma unroll
    for (int nf = 0; nf < 4; ++nf) {
      float pv = exp2f(s[nf][j] - mn);
      s[nf][j] = pv; sum += pv;
    }
    ps[j] = sum;
    l_run[j] *= al;
    #pragma unroll
    for (int nf2 = 0; nf2 < 8; ++nf2) oa[nf2][j] *= al;
  }
  #pragma unroll
  for (int off = 1; off < 16; off <<= 1)
    #pragma unroll
    for (int j = 0; j < 4; ++j) ps[j] += __shfl_xor(ps[j], off);
  #pragma unroll
  for (int j = 0; j < 4; ++j) l_run[j] += ps[j];
  #pragma unroll
  for (int j = 0; j < 4; ++j) {
    int row = lg * 4 + j;
    #pragma unroll
    for (int nf = 0; nf < 4; ++nf) {
      int byte = (row * 128 + (nf * 16 + lrow) * 2) ^ ((row & 7) << 4);
      *(u16*)((char*)PsW + byte) = f2b(s[nf][j]);
    }
  }
}

__global__ __launch_bounds__(256) void attn_k(const u16* __restrict__ qkv,
                                              u16* __restrict__ out) {
  __shared__ u16 Ks[2][64 * 128];
  __shared__ u16 Vt[2][128 * 64];
  __shared__ u16 Ps[4][2][16 * 64];
  int t = threadIdx.x, lane = t & 63, w = t >> 6;
  int lrow = lane & 15, lg = lane >> 4;
  int p = blockIdx.x, bh = blockIdx.y;
  int b = bh / 7, h = bh % 7;
  int tA = p, tB = 31 - p;
  int qA = tA * 64 + w * 16, qB = tB * 64 + w * 16;
  const u16* base = qkv + (size_t)b * 2048 * 1152;
  const u16* kb = base + 896;
  const u16* vb = base + 1024;

  bf16x8 qfA[4], qfB[4];
  #pragma unroll
  for (int kk = 0; kk < 4; ++kk) {
    qfA[kk] = *(const bf16x8*)(base + (size_t)(qA + lrow) * 1152 + h * 128 + kk * 32 + lg * 8);
    qfB[kk] = *(const bf16x8*)(base + (size_t)(qB + lrow) * 1152 + h * 128 + kk * 32 + lg * 8);
  }
  f32x4 oaA[8] = {}, oaB[8] = {};
  float mA[4], lA[4], mB[4], lB[4];
  #pragma unroll
  for (int j = 0; j < 4; ++j) { mA[j] = -1e30f; lA[j] = 0.0f; mB[j] = -1e30f; lB[j] = 0.0f; }

  stageK_sw(Ks[0], kb, 0, t);
  { u16x8 vr[4]; loadV(vr, vb, 0, t); writeVt(Vt[0], vr, t); }
  __syncthreads();

  int cur = 0;
  int ktmax = tB;
  for (int kt = 0; kt <= ktmax; ++kt) {
    bool pre = kt < ktmax;
    u16x8 vr2[4];
    if (pre) { stageK_sw(Ks[cur ^ 1], kb, (kt + 1) * 64, t); loadV(vr2, vb, (kt + 1) * 64, t); }

    bool doA = (kt <= tA);
    int k0 = kt * 64;
    const u16* KsC = Ks[cur];
    const u16* VtC = Vt[cur];

    f32x4 saA[4] = {}, saB[4] = {};
    #pragma unroll
    for (int nf = 0; nf < 4; ++nf) {
      bf16x8 kf[4];
      #pragma unroll
      for (int kk = 0; kk < 4; ++kk)
        kf[kk] = ldSw(KsC, nf * 16 + lrow, 256, kk * 64 + lg * 16);
      #pragma unroll
      for (int kk = 0; kk < 4; ++kk)
        saB[nf] = mfma16(qfB[kk], kf[kk], saB[nf]);
      if (doA)
        #pragma unroll
        for (int kk = 0; kk < 4; ++kk)
          saA[nf] = mfma16(qfA[kk], kf[kk], saA[nf]);
    }

    if (doA) smax_tile(saA, qA, k0, kt == tA, mA, lA, oaA, Ps[w][0], lrow, lg);
    smax_tile(saB, qB, k0, kt == tB, mB, lB, oaB, Ps[w][1], lrow, lg);

    bf16x8 pfA[2], pfB[2];
    #pragma unroll
    for (int ks = 0; ks < 2; ++ks) {
      pfB[ks] = ldSw(Ps[w][1], lrow, 128, ks * 64 + lg * 16);
      if (doA) pfA[ks] = ldSw(Ps[w][0], lrow, 128, ks * 64 + lg * 16);
    }
    #pragma unroll
    for (int ks = 0; ks < 2; ++ks) {
      bf16x8 vf[8];
      #pragma unroll
      for (int nf2 = 0; nf2 < 8; ++nf2)
        vf[nf2] = ldSw(VtC, nf2 * 16 + lrow, 128, ks * 64 + lg * 16);
      #pragma unroll
      for (int nf2 = 0; nf2 < 8; ++nf2)
        oaB[nf2] = mfma16(pfB[ks], vf[nf2], oaB[nf2]);
      if (doA)
        #pragma unroll
        for (int nf2 = 0; nf2 < 8; ++nf2)
          oaA[nf2] = mfma16(pfA[ks], vf[nf2], oaA[nf2]);
    }

    if (pre) writeVt(Vt[cur ^ 1], vr2, t);
    __syncthreads();
    cur ^= 1;
  }

  #pragma unroll
  for (int tile = 0; tile < 2; ++tile) {
    int q0 = tile ? qB : qA;
    const f32x4* oa = tile ? oaB : oaA;
    const float* l = tile ? lB : lA;
    u16* ob = out + ((size_t)b * 2048 + q0) * 896 + h * 128;
    #pragma unroll
    for (int j = 0; j < 4; ++j) {
      float rl = 1.0f / l[j];
      #pragma unroll
      for (int nf2 = 0; nf2 < 8; ++nf2)
        ob[(size_t)(lg * 4 + j) * 896 + nf2 * 16 + lrow] = f2b(oa[nf2][j] * rl);
    }
  }
}

// ---------------------------------------------------------------------------
extern "C" void kernel_launch(void* const* d_in, const int* in_sizes, int n_in,
                              void* d_out, int out_size, void* d_ws, size_t ws_size,
                              hipStream_t stream) {
  const int nX = 4096 * 896, nWQ = 896 * 896, nBQ = 896, nWK = 128 * 896, nBK = 128;
  const int nWV = 128 * 896, nBV = 128, nWO = 896 * 896;
  const int nWG = 4864 * 896, nWU = 4864 * 896, nWD = 896 * 4864;
  const int nLN = 896, nCS = 2048 * 128;

  u16* ws = (u16*)d_ws;
  int* flag = (int*)ws;
  size_t off = 16;
  auto alloc = [&](size_t n) { u16* p = ws + off; off += n; return p; };
  u16* cx   = alloc(nX);
  u16* cwq  = alloc(nWQ);  u16* cbq = alloc(nBQ);
  u16* cwk  = alloc(nWK);  u16* cbk = alloc(nBK);
  u16* cwv  = alloc(nWV);  u16* cbv = alloc(nBV);
  u16* cwo  = alloc(nWO);
  u16* cwg  = alloc(nWG);  u16* cwu = alloc(nWU);  u16* cwd = alloc(nWD);
  u16* cln1 = alloc(nLN);  u16* cln2 = alloc(nLN);
  u16* ccos = alloc(nCS);  u16* csin = alloc(nCS);
  u16* h    = alloc(4096 * 896);     // dead after gateup -> P0 (fp32, spills into dead qkv)
  u16* qkv  = alloc(4096 * 1152);    // dead after attn
  u16* attn = alloc(4096 * 896);     // dead after wo    -> P1 (bf16)
  u16* x2   = alloc(4096 * 896);
  u16* act  = alloc((size_t)4096 * 4864);

  detect_k<<<1, 256, 0, stream>>>((const unsigned int*)d_in[0], flag);

  CvtJobs jobs;
  const void* srcs[15] = { d_in[0], d_in[1], d_in[2], d_in[3], d_in[4], d_in[5],
                           d_in[6], d_in[7], d_in[8], d_in[9], d_in[10],
                           d_in[11], d_in[12], d_in[14], d_in[15] };
  u16* dsts[15] = { cx, cwq, cbq, cwk, cbk, cwv, cbv, cwo, cwg, cwu, cwd,
                    cln1, cln2, ccos, csin };
  int  ns[15]   = { nX, nWQ, nBQ, nWK, nBK, nWV, nBV, nWO, nWG, nWU, nWD,
                    nLN, nLN, nCS, nCS };
  for (int i = 0; i < 15; ++i) { jobs.j[i].src = srcs[i]; jobs.j[i].dst = dsts[i]; jobs.j[i].n = ns[i]; }
  convert_k<<<dim3(2128, 15), 256, 0, stream>>>(jobs, flag);

  rmsnorm_k <<<4096, 448, 0, stream>>>(cx, cln1, h);
  gemm_qkv  <<<dim3(9, 32),  256, 0, stream>>>(h, cwq, cbq, cwk, cbk, cwv, cbv, qkv);
  rope_k    <<<dim3(2, 4096), 256, 0, stream>>>(qkv, ccos, csin);
  attn_k    <<<dim3(16, 14), 256, 0, stream>>>(qkv, attn);
  gemm_bt<true, false> <<<dim3(7, 32), 256, 0, stream>>>(attn, cwo, cx, (void*)x2, flag, 896, 896);
  rmsnorm_k <<<4096, 448, 0, stream>>>(x2, cln2, h);
  gemm_gateup256 <<<608, 512, 0, stream>>>(h, cwg, cwu, act);
  // down-proj split-K=2: P0 = fp32 partial(+x2) in [h..qkv) region,
  // P1 = bf16 partial in attn. Then reduce -> d_out (dyn dtype).
  gemm_down_splitk <<<dim3(7, 32, 2), 256, 0, stream>>>(act, cwd, x2, (float*)h, attn);
  reduce_out_k <<<3584, 256, 0, stream>>>((const float*)h, attn, d_out, flag);
}